// Round 4
// baseline (1791.548 us; speedup 1.0000x reference)
//
#include <hip/hip_runtime.h>
#include <stdint.h>

#define DF 128

typedef __attribute__((ext_vector_type(8))) short bf16x8;
typedef __attribute__((ext_vector_type(4))) float f32x4;

__device__ __forceinline__ float bf2f(uint32_t b){ union{uint32_t u; float f;} c; c.u = b<<16; return c.f; }
__device__ __forceinline__ uint16_t f2bf(float f){
  union{float f; uint32_t u;} c; c.f = f;
  return (uint16_t)((c.u + 0x7fffu + ((c.u>>16)&1u))>>16);
}

// ---------------- CSR build (all 4 edge sets in one padded layout) ----------------
__global__ __launch_bounds__(256) void k_zero(int* __restrict__ p, int n){
  int i = blockIdx.x*256 + threadIdx.x;
  if (i < n) p[i] = 0;
}

__global__ __launch_bounds__(256) void k_count_all(
    const int* __restrict__ d0, const int* __restrict__ d1,
    const int* __restrict__ d2, const int* __restrict__ d3,
    int* __restrict__ deg, int Ep, int Es, int A1, int A2, int A3){
  int Etot = 2*Ep + 2*Es;
  for (int e = blockIdx.x*256 + threadIdx.x; e < Etot; e += gridDim.x*256){
    if (e < Ep)            atomicAdd(&deg[d0[e]], 1);
    else if (e < 2*Ep)     atomicAdd(&deg[A1 + d1[e-Ep]], 1);
    else if (e < 2*Ep+Es)  atomicAdd(&deg[A2 + d2[e-2*Ep]], 1);
    else                   atomicAdd(&deg[A3 + d3[e-2*Ep-Es]], 1);
  }
}

__global__ __launch_bounds__(256) void k_scan1(const int* __restrict__ in, int* __restrict__ out,
                                               int* __restrict__ bsum, int n){
  __shared__ int lds[256];
  int t = threadIdx.x;
  int base = blockIdx.x*1024 + t*4;
  int v0 = (base+0<n)?in[base+0]:0, v1 = (base+1<n)?in[base+1]:0;
  int v2 = (base+2<n)?in[base+2]:0, v3 = (base+3<n)?in[base+3]:0;
  int ts = v0+v1+v2+v3;
  lds[t] = ts; __syncthreads();
  for (int off=1; off<256; off<<=1){
    int x = (t>=off)?lds[t-off]:0; __syncthreads();
    lds[t] += x; __syncthreads();
  }
  int incl = lds[t];
  if (t==255) bsum[blockIdx.x] = incl;
  int run = incl - ts;
  if (base+0<n) out[base+0]=run; run+=v0;
  if (base+1<n) out[base+1]=run; run+=v1;
  if (base+2<n) out[base+2]=run; run+=v2;
  if (base+3<n) out[base+3]=run;
}

__global__ __launch_bounds__(256) void k_scan2(int* __restrict__ s, int nb){
  __shared__ int lds[256];
  __shared__ int carry;
  int t = threadIdx.x;
  if (t==0) carry = 0;
  __syncthreads();
  for (int b0=0; b0<nb; b0+=1024){
    int base = b0 + t*4;
    int v0 = (base+0<nb)?s[base+0]:0, v1 = (base+1<nb)?s[base+1]:0;
    int v2 = (base+2<nb)?s[base+2]:0, v3 = (base+3<nb)?s[base+3]:0;
    int ts = v0+v1+v2+v3;
    lds[t] = ts; __syncthreads();
    for (int off=1; off<256; off<<=1){
      int x = (t>=off)?lds[t-off]:0; __syncthreads();
      lds[t] += x; __syncthreads();
    }
    int incl = lds[t];
    int tot  = lds[255];
    int c0   = carry;
    __syncthreads();
    int run = incl - ts + c0;
    if (base+0<nb) s[base+0]=run; run+=v0;
    if (base+1<nb) s[base+1]=run; run+=v1;
    if (base+2<nb) s[base+2]=run; run+=v2;
    if (base+3<nb) s[base+3]=run;
    if (t==0) carry = c0 + tot;
    __syncthreads();
  }
}

// rp[i] = scan[i]+bsum - set_base ; cur[i] = same
__global__ __launch_bounds__(256) void k_add_all(int* __restrict__ rp, int* __restrict__ cur,
                                                 const int* __restrict__ bsum,
                                                 int A1, int A2, int A3,
                                                 int B1, int B2, int B3, int NT){
  int i = blockIdx.x*256 + threadIdx.x;
  if (i >= NT) return;
  int b = (i < A1) ? 0 : (i < A2) ? B1 : (i < A3) ? B2 : B3;
  int v = rp[i] + bsum[i>>10] - b;
  rp[i] = v; cur[i] = v;
}

__global__ __launch_bounds__(256) void k_fill_all(
    const int* __restrict__ s0, const int* __restrict__ d0,
    const int* __restrict__ s1, const int* __restrict__ d1,
    const int* __restrict__ s2, const int* __restrict__ d2,
    const int* __restrict__ s3, const int* __restrict__ d3,
    int* __restrict__ cur,
    int* __restrict__ c0, int* __restrict__ c1, int* __restrict__ c2, int* __restrict__ c3,
    int Ep, int Es, int A1, int A2, int A3){
  int Etot = 2*Ep + 2*Es;
  for (int e = blockIdx.x*256 + threadIdx.x; e < Etot; e += gridDim.x*256){
    if (e < Ep){            int p = atomicAdd(&cur[d0[e]], 1);                 c0[p] = s0[e]; }
    else if (e < 2*Ep){     int q = e-Ep;      int p = atomicAdd(&cur[A1+d1[q]], 1); c1[p] = s1[q]; }
    else if (e < 2*Ep+Es){  int q = e-2*Ep;    int p = atomicAdd(&cur[A2+d2[q]], 1); c2[p] = s2[q]; }
    else{                   int q = e-2*Ep-Es; int p = atomicAdd(&cur[A3+d3[q]], 1); c3[p] = s3[q]; }
  }
}

// ---------------- f32 -> bf16 feature cast ----------------
__global__ __launch_bounds__(256) void k_cast(const float* __restrict__ xp, const float* __restrict__ xs,
                                              uint16_t* __restrict__ hp, uint16_t* __restrict__ hs,
                                              int npE, int total4){
  int i = blockIdx.x*256 + threadIdx.x;
  if (i >= total4) return;
  int e = i*4;
  const float* src; uint16_t* dst; int o;
  if (e < npE){ src = xp; dst = hp; o = e; }
  else        { src = xs; dst = hs; o = e - npE; }
  float4 v = *(const float4*)(src + o);
  ushort4 u;
  u.x = f2bf(v.x); u.y = f2bf(v.y); u.z = f2bf(v.z); u.w = f2bf(v.w);
  *(ushort4*)(dst + o) = u;
}

// ---------------- weight transpose+cast: WT_bf16[n*128+k] = W_f32[(kOff+k)*128+n] ----------------
__global__ __launch_bounds__(256) void k_transpose_all(
    const float* __restrict__ Wpf, const float* __restrict__ Wpb,
    const float* __restrict__ Wsf, const float* __restrict__ Wsb,
    const float* __restrict__ Wcp, const float* __restrict__ Wcs,
    uint16_t* __restrict__ wt, int K){
  int idx = blockIdx.x*256 + threadIdx.x;
  if (idx >= K*8*16384) return;
  int ls = idx >> 14, layer = ls >> 3, slot = ls & 7;
  int within = idx & 16383, n = within >> 7, k = within & 127;
  const float* src; int kOff = 0;
  switch (slot){
    case 0: src = Wpf + (size_t)layer*16384; break;
    case 1: src = Wpb + (size_t)layer*16384; break;
    case 2: src = Wsf + (size_t)layer*16384; break;
    case 3: src = Wsb + (size_t)layer*16384; break;
    case 4: src = Wcp + (size_t)layer*32768; break;
    case 5: src = Wcp + (size_t)layer*32768; kOff = 128; break;
    case 6: src = Wcs + (size_t)layer*32768; break;
    default: src = Wcs + (size_t)layer*32768; kOff = 128; break;
  }
  wt[idx] = f2bf(src[(size_t)(kOff + k)*DF + n]);
}

// ---------------- fused segment-mean aggregation (1 wave / dst row) ----------------
__global__ __launch_bounds__(256) void k_agg_all(
    const uint16_t* __restrict__ hp, const uint16_t* __restrict__ hs,
    const int* __restrict__ rpAll, int A1, int A2, int A3,
    const int* __restrict__ c0, const int* __restrict__ c1,
    const int* __restrict__ c2, const int* __restrict__ c3,
    uint16_t* __restrict__ o0, uint16_t* __restrict__ o1,
    uint16_t* __restrict__ o2, uint16_t* __restrict__ o3,
    int Np, int Ns, int gp, int gs){
  int b = blockIdx.x, w = threadIdx.x >> 6, lane = threadIdx.x & 63;
  const uint16_t* x; const int* rp; const int* col; uint16_t* out; int n, row;
  if (b < gp)            { x=hp; rp=rpAll;    col=c0; out=o0; n=Np; row=b*4+w; }
  else if (b < 2*gp)     { x=hp; rp=rpAll+A1; col=c1; out=o1; n=Np; row=(b-gp)*4+w; }
  else if (b < 2*gp+gs)  { x=hs; rp=rpAll+A2; col=c2; out=o2; n=Ns; row=(b-2*gp)*4+w; }
  else                   { x=hs; rp=rpAll+A3; col=c3; out=o3; n=Ns; row=(b-2*gp-gs)*4+w; }
  if (row >= n) return;
  int beg = rp[row], end = rp[row+1];
  float a0 = 0.f, a1 = 0.f;
  for (int e = beg; e < end; ++e){
    int s = col[e];
    uint32_t u = *(const uint32_t*)(x + ((size_t)s<<7) + (lane<<1));
    a0 += bf2f(u & 0xffffu);
    a1 += bf2f(u >> 16);
  }
  float inv = 1.0f / fmaxf((float)(end - beg), 1.0f);
  uint32_t pk = (uint32_t)f2bf(a0*inv) | ((uint32_t)f2bf(a1*inv) << 16);
  *(uint32_t*)(out + ((size_t)row<<7) + (lane<<1)) = pk;
}

// ---------------- MFMA GEMM body: out = [act](A1@W1' (+ A2@W2') + bias) ----------------
// WT[n][k] 128x128 bf16. BM=64 (4 waves x 16 rows). XOR-swizzled LDS (16B chunk ^ (row&7)).
template<int HAS2, int ACT, int OUTF32>
__device__ __forceinline__ void gemm_body(
    const uint16_t* __restrict__ A1, const uint16_t* __restrict__ A2,
    const uint16_t* __restrict__ W1, const uint16_t* __restrict__ W2,
    const float* __restrict__ bias, uint16_t* __restrict__ outb,
    float* __restrict__ outf, int M, int m0){
  __shared__ uint16_t sA[64][128];
  __shared__ uint16_t sW[128][128];
  int t = threadIdx.x, w = t >> 6, lane = t & 63;

  f32x4 acc[8];
#pragma unroll
  for (int n=0; n<8; ++n) acc[n] = (f32x4){0.f,0.f,0.f,0.f};

  const uint16_t* Ap = A1;
  const uint16_t* Wp = W1;
#pragma unroll
  for (int pass=0; pass < (HAS2?2:1); ++pass){
    if (pass == 1){ Ap = A2; Wp = W2; __syncthreads(); }
#pragma unroll
    for (int i=0; i<4; ++i){            // stage A tile 64x128
      int c = t + i*256, r = c >> 4, ch = c & 15;
      int gr = m0 + r;
      uint4 val = {0u,0u,0u,0u};
      if (gr < M) val = *(const uint4*)(Ap + (size_t)gr*DF + (ch<<3));
      *(uint4*)(&sA[r][(ch ^ (r&7)) << 3]) = val;
    }
#pragma unroll
    for (int i=0; i<8; ++i){            // stage WT 128x128
      int c = t + i*256, r = c >> 4, ch = c & 15;
      *(uint4*)(&sW[r][(ch ^ (r&7)) << 3]) = *(const uint4*)(Wp + (size_t)r*DF + (ch<<3));
    }
    __syncthreads();

    int ar = (w << 4) + (lane & 15);
    int q  = lane >> 4;
#pragma unroll
    for (int kc=0; kc<4; ++kc){
      int ch = kc*4 + q;
      bf16x8 afrag = *(const bf16x8*)(&sA[ar][(ch ^ (ar&7)) << 3]);
#pragma unroll
      for (int n=0; n<8; ++n){
        int br = (n << 4) + (lane & 15);
        bf16x8 bfrag = *(const bf16x8*)(&sW[br][(ch ^ (br&7)) << 3]);
        acc[n] = __builtin_amdgcn_mfma_f32_16x16x32_bf16(afrag, bfrag, acc[n], 0, 0, 0);
      }
    }
  }

  int row0 = m0 + (w << 4) + ((lane >> 4) << 2);
  int cb = lane & 15;
#pragma unroll
  for (int n=0; n<8; ++n){
    int colv = (n << 4) + cb;
    float bv = bias[colv];
#pragma unroll
    for (int r=0; r<4; ++r){
      int grow = row0 + r;
      if (grow < M){
        float v = acc[n][r] + bv;
        if (ACT) v = (v > 0.f) ? v : 0.01f*v;
        if (OUTF32) outf[(size_t)grow*DF + colv] = v;
        else        outb[(size_t)grow*DF + colv] = f2bf(v);
      }
    }
  }
}

// fused per-direction linear+LeakyReLU (in place on agg buffers)
__global__ __launch_bounds__(256) void k_dir_all(
    uint16_t* Afp, uint16_t* Abp, uint16_t* Afs, uint16_t* Abs,
    const uint16_t* w0, const uint16_t* w1, const uint16_t* w2, const uint16_t* w3,
    const float* b0, const float* b1, const float* b2, const float* b3,
    int Np, int Ns, int bp, int bs){
  int b = blockIdx.x;
  uint16_t* A; const uint16_t* W; const float* bias; int M, lb;
  if (b < bp)            { A=Afp; W=w0; bias=b0; M=Np; lb=b; }
  else if (b < 2*bp)     { A=Abp; W=w1; bias=b1; M=Np; lb=b-bp; }
  else if (b < 2*bp+bs)  { A=Afs; W=w2; bias=b2; M=Ns; lb=b-2*bp; }
  else                   { A=Abs; W=w3; bias=b3; M=Ns; lb=b-2*bp-bs; }
  gemm_body<0,1,0>(A, nullptr, W, nullptr, bias, A, nullptr, M, lb*64);
}

// fused concat-FC: [f|b] @ Wc + bias. OUTF32=1 on last layer (writes d_out f32).
template<int OUTF32>
__global__ __launch_bounds__(256) void k_concat(
    const uint16_t* Afp, const uint16_t* Abp, const uint16_t* Afs, const uint16_t* Abs,
    const uint16_t* w4, const uint16_t* w5, const uint16_t* w6, const uint16_t* w7,
    const float* bcp, const float* bcs,
    uint16_t* hpb, uint16_t* hsb, float* outP, float* outS,
    int Np, int Ns, int bp, int bs){
  int b = blockIdx.x;
  const uint16_t *A1, *A2, *W1, *W2; const float* bias;
  uint16_t* ob; float* of; int M, lb;
  if (b < bp){ A1=Afp; A2=Abp; W1=w4; W2=w5; bias=bcp; ob=hpb; of=outP; M=Np; lb=b; }
  else       { A1=Afs; A2=Abs; W1=w6; W2=w7; bias=bcs; ob=hsb; of=outS; M=Ns; lb=b-bp; }
  gemm_body<1,0,OUTF32>(A1, A2, W1, W2, bias, ob, of, M, lb*64);
}

// ---------------- host ----------------
extern "C" void kernel_launch(void* const* d_in, const int* in_sizes, int n_in,
                              void* d_out, int out_size, void* d_ws, size_t ws_size,
                              hipStream_t stream){
  const float* x_paper = (const float*)d_in[0];
  const float* x_snap  = (const float*)d_in[1];
  const int* src_pf = (const int*)d_in[2]; const int* dst_pf = (const int*)d_in[3];
  const int* src_pb = (const int*)d_in[4]; const int* dst_pb = (const int*)d_in[5];
  const int* src_sf = (const int*)d_in[6]; const int* dst_sf = (const int*)d_in[7];
  const int* src_sb = (const int*)d_in[8]; const int* dst_sb = (const int*)d_in[9];
  const float* Wpf = (const float*)d_in[10]; const float* bpf = (const float*)d_in[11];
  const float* Wsf = (const float*)d_in[12]; const float* bsf = (const float*)d_in[13];
  const float* Wpb = (const float*)d_in[14]; const float* bpb = (const float*)d_in[15];
  const float* Wsb = (const float*)d_in[16]; const float* bsb = (const float*)d_in[17];
  const float* Wcp = (const float*)d_in[18]; const float* bcp = (const float*)d_in[19];
  const float* Wcs = (const float*)d_in[20]; const float* bcs = (const float*)d_in[21];

  const int Np = in_sizes[0]/DF, Ns = in_sizes[1]/DF;
  const int Ep = in_sizes[2],    Es = in_sizes[6];
  const int K  = in_sizes[10]/(DF*DF);

  // padded concatenated layout for the 4 degree/rowptr sets
  const int P1 = ((Np + 1 + 1023)/1024)*1024;
  const int Ps = ((Ns + 1 + 1023)/1024)*1024;
  const int A1 = P1, A2 = 2*P1, A3 = 2*P1 + Ps, NT = 2*P1 + 2*Ps;
  const int B1 = Ep, B2 = 2*Ep, B3 = 2*Ep + Es;

  uint8_t* base = (uint8_t*)d_ws;
  size_t off = 0;
  auto carve = [&](size_t bytes)->void*{
    void* p = base + off;
    off = (off + bytes + 255) & ~(size_t)255;
    return p;
  };

  int* degAll = (int*)carve((size_t)NT*4);
  int* rpAll  = (int*)carve((size_t)NT*4);
  int* curAll = (int*)carve((size_t)NT*4);
  int* bsum   = (int*)carve(4096*4);
  int* col0 = (int*)carve((size_t)Ep*4);
  int* col1 = (int*)carve((size_t)Ep*4);
  int* col2 = (int*)carve((size_t)Es*4);
  int* col3 = (int*)carve((size_t)Es*4);
  uint16_t* wt   = (uint16_t*)carve((size_t)K*8*16384*2);
  uint16_t* hp_b = (uint16_t*)carve((size_t)Np*DF*2);
  uint16_t* hs_b = (uint16_t*)carve((size_t)Ns*DF*2);
  uint16_t* Afp  = (uint16_t*)carve((size_t)Np*DF*2);
  uint16_t* Abp  = (uint16_t*)carve((size_t)Np*DF*2);
  uint16_t* Afs  = (uint16_t*)carve((size_t)Ns*DF*2);
  uint16_t* Abs  = (uint16_t*)carve((size_t)Ns*DF*2);

  auto wts = [&](int layer, int slot)->const uint16_t*{
    return wt + ((size_t)layer*8 + slot)*16384;
  };

  const int Etot = 2*Ep + 2*Es;
  int eblk = (Etot + 255)/256; if (eblk > 2048) eblk = 2048;

  // CSR build (6 launches)
  k_zero<<<(NT+255)/256, 256, 0, stream>>>(degAll, NT);
  k_count_all<<<eblk, 256, 0, stream>>>(dst_pf, dst_pb, dst_sf, dst_sb, degAll, Ep, Es, A1, A2, A3);
  k_scan1<<<NT/1024, 256, 0, stream>>>(degAll, rpAll, bsum, NT);
  k_scan2<<<1, 256, 0, stream>>>(bsum, NT/1024);
  k_add_all<<<(NT+255)/256, 256, 0, stream>>>(rpAll, curAll, bsum, A1, A2, A3, B1, B2, B3, NT);
  k_fill_all<<<eblk, 256, 0, stream>>>(src_pf, dst_pf, src_pb, dst_pb, src_sf, dst_sf, src_sb, dst_sb,
                                       curAll, col0, col1, col2, col3, Ep, Es, A1, A2, A3);

  // feature cast + weight transpose/cast
  const int npE = Np*DF, total4 = (Np + Ns)*DF/4;
  k_cast<<<(total4+255)/256, 256, 0, stream>>>(x_paper, x_snap, hp_b, hs_b, npE, total4);
  k_transpose_all<<<(K*8*16384+255)/256, 256, 0, stream>>>(Wpf, Wpb, Wsf, Wsb, Wcp, Wcs, wt, K);

  float* outP = (float*)d_out;
  float* outS = outP + (size_t)Np*DF;
  const int gp = (Np+3)/4, gs = (Ns+3)/4;
  const int bp = (Np+63)/64, bs = (Ns+63)/64;

  for (int i=0; i<K; ++i){
    k_agg_all<<<2*gp + 2*gs, 256, 0, stream>>>(hp_b, hs_b, rpAll, A1, A2, A3,
                                               col0, col1, col2, col3,
                                               Afp, Abp, Afs, Abs, Np, Ns, gp, gs);
    k_dir_all<<<2*bp + 2*bs, 256, 0, stream>>>(Afp, Abp, Afs, Abs,
                                               wts(i,0), wts(i,1), wts(i,2), wts(i,3),
                                               bpf + (size_t)i*DF, bpb + (size_t)i*DF,
                                               bsf + (size_t)i*DF, bsb + (size_t)i*DF,
                                               Np, Ns, bp, bs);
    if (i == K-1)
      k_concat<1><<<bp + bs, 256, 0, stream>>>(Afp, Abp, Afs, Abs,
                                               wts(i,4), wts(i,5), wts(i,6), wts(i,7),
                                               bcp + (size_t)i*DF, bcs + (size_t)i*DF,
                                               hp_b, hs_b, outP, outS, Np, Ns, bp, bs);
    else
      k_concat<0><<<bp + bs, 256, 0, stream>>>(Afp, Abp, Afs, Abs,
                                               wts(i,4), wts(i,5), wts(i,6), wts(i,7),
                                               bcp + (size_t)i*DF, bcs + (size_t)i*DF,
                                               hp_b, hs_b, outP, outS, Np, Ns, bp, bs);
  }
}

// Round 6
// 1375.489 us; speedup vs baseline: 1.3025x; 1.3025x over previous
//
#include <hip/hip_runtime.h>
#include <stdint.h>

#define DF 128

typedef __attribute__((ext_vector_type(8))) short bf16x8;
typedef __attribute__((ext_vector_type(4))) float f32x4;

__device__ __forceinline__ float bf2f(uint32_t b){ union{uint32_t u; float f;} c; c.u = b<<16; return c.f; }
__device__ __forceinline__ uint16_t f2bf(float f){
  union{float f; uint32_t u;} c; c.f = f;
  return (uint16_t)((c.u + 0x7fffu + ((c.u>>16)&1u))>>16);
}

// ---------------- CSR build (all 4 edge sets in one padded layout) ----------------
__global__ __launch_bounds__(256) void k_zero(int* __restrict__ p, int n){
  int i = blockIdx.x*256 + threadIdx.x;
  if (i < n) p[i] = 0;
}

__global__ __launch_bounds__(256) void k_count_all(
    const int* __restrict__ d0, const int* __restrict__ d1,
    const int* __restrict__ d2, const int* __restrict__ d3,
    int* __restrict__ deg, int Ep, int Es, int A1, int A2, int A3){
  int Etot = 2*Ep + 2*Es;
  for (int e = blockIdx.x*256 + threadIdx.x; e < Etot; e += gridDim.x*256){
    if (e < Ep)            atomicAdd(&deg[d0[e]], 1);
    else if (e < 2*Ep)     atomicAdd(&deg[A1 + d1[e-Ep]], 1);
    else if (e < 2*Ep+Es)  atomicAdd(&deg[A2 + d2[e-2*Ep]], 1);
    else                   atomicAdd(&deg[A3 + d3[e-2*Ep-Es]], 1);
  }
}

__global__ __launch_bounds__(256) void k_scan1(const int* __restrict__ in, int* __restrict__ out,
                                               int* __restrict__ bsum, int n){
  __shared__ int lds[256];
  int t = threadIdx.x;
  int base = blockIdx.x*1024 + t*4;
  int v0 = (base+0<n)?in[base+0]:0, v1 = (base+1<n)?in[base+1]:0;
  int v2 = (base+2<n)?in[base+2]:0, v3 = (base+3<n)?in[base+3]:0;
  int ts = v0+v1+v2+v3;
  lds[t] = ts; __syncthreads();
  for (int off=1; off<256; off<<=1){
    int x = (t>=off)?lds[t-off]:0; __syncthreads();
    lds[t] += x; __syncthreads();
  }
  int incl = lds[t];
  if (t==255) bsum[blockIdx.x] = incl;
  int run = incl - ts;
  if (base+0<n) out[base+0]=run; run+=v0;
  if (base+1<n) out[base+1]=run; run+=v1;
  if (base+2<n) out[base+2]=run; run+=v2;
  if (base+3<n) out[base+3]=run;
}

__global__ __launch_bounds__(256) void k_scan2(int* __restrict__ s, int nb){
  __shared__ int lds[256];
  __shared__ int carry;
  int t = threadIdx.x;
  if (t==0) carry = 0;
  __syncthreads();
  for (int b0=0; b0<nb; b0+=1024){
    int base = b0 + t*4;
    int v0 = (base+0<nb)?s[base+0]:0, v1 = (base+1<nb)?s[base+1]:0;
    int v2 = (base+2<nb)?s[base+2]:0, v3 = (base+3<nb)?s[base+3]:0;
    int ts = v0+v1+v2+v3;
    lds[t] = ts; __syncthreads();
    for (int off=1; off<256; off<<=1){
      int x = (t>=off)?lds[t-off]:0; __syncthreads();
      lds[t] += x; __syncthreads();
    }
    int incl = lds[t];
    int tot  = lds[255];
    int c0   = carry;
    __syncthreads();
    int run = incl - ts + c0;
    if (base+0<nb) s[base+0]=run; run+=v0;
    if (base+1<nb) s[base+1]=run; run+=v1;
    if (base+2<nb) s[base+2]=run; run+=v2;
    if (base+3<nb) s[base+3]=run;
    if (t==0) carry = c0 + tot;
    __syncthreads();
  }
}

__global__ __launch_bounds__(256) void k_add_all(int* __restrict__ rp, int* __restrict__ cur,
                                                 const int* __restrict__ bsum,
                                                 int A1, int A2, int A3,
                                                 int B1, int B2, int B3, int NT){
  int i = blockIdx.x*256 + threadIdx.x;
  if (i >= NT) return;
  int b = (i < A1) ? 0 : (i < A2) ? B1 : (i < A3) ? B2 : B3;
  int v = rp[i] + bsum[i>>10] - b;
  rp[i] = v; cur[i] = v;
}

__global__ __launch_bounds__(256) void k_fill_all(
    const int* __restrict__ s0, const int* __restrict__ d0,
    const int* __restrict__ s1, const int* __restrict__ d1,
    const int* __restrict__ s2, const int* __restrict__ d2,
    const int* __restrict__ s3, const int* __restrict__ d3,
    int* __restrict__ cur,
    int* __restrict__ c0, int* __restrict__ c1, int* __restrict__ c2, int* __restrict__ c3,
    int Ep, int Es, int A1, int A2, int A3){
  int Etot = 2*Ep + 2*Es;
  for (int e = blockIdx.x*256 + threadIdx.x; e < Etot; e += gridDim.x*256){
    if (e < Ep){            int p = atomicAdd(&cur[d0[e]], 1);                 c0[p] = s0[e]; }
    else if (e < 2*Ep){     int q = e-Ep;      int p = atomicAdd(&cur[A1+d1[q]], 1); c1[p] = s1[q]; }
    else if (e < 2*Ep+Es){  int q = e-2*Ep;    int p = atomicAdd(&cur[A2+d2[q]], 1); c2[p] = s2[q]; }
    else{                   int q = e-2*Ep-Es; int p = atomicAdd(&cur[A3+d3[q]], 1); c3[p] = s3[q]; }
  }
}

// ---------------- f32 -> bf16 feature cast ----------------
__global__ __launch_bounds__(256) void k_cast(const float* __restrict__ xp, const float* __restrict__ xs,
                                              uint16_t* __restrict__ hp, uint16_t* __restrict__ hs,
                                              int npE, int total4){
  int i = blockIdx.x*256 + threadIdx.x;
  if (i >= total4) return;
  int e = i*4;
  const float* src; uint16_t* dst; int o;
  if (e < npE){ src = xp; dst = hp; o = e; }
  else        { src = xs; dst = hs; o = e - npE; }
  float4 v = *(const float4*)(src + o);
  ushort4 u;
  u.x = f2bf(v.x); u.y = f2bf(v.y); u.z = f2bf(v.z); u.w = f2bf(v.w);
  *(ushort4*)(dst + o) = u;
}

// ---------------- weight transpose+cast ----------------
__global__ __launch_bounds__(256) void k_transpose_all(
    const float* __restrict__ Wpf, const float* __restrict__ Wpb,
    const float* __restrict__ Wsf, const float* __restrict__ Wsb,
    const float* __restrict__ Wcp, const float* __restrict__ Wcs,
    uint16_t* __restrict__ wt, int K){
  int idx = blockIdx.x*256 + threadIdx.x;
  if (idx >= K*8*16384) return;
  int ls = idx >> 14, layer = ls >> 3, slot = ls & 7;
  int within = idx & 16383, n = within >> 7, k = within & 127;
  const float* src; int kOff = 0;
  switch (slot){
    case 0: src = Wpf + (size_t)layer*16384; break;
    case 1: src = Wpb + (size_t)layer*16384; break;
    case 2: src = Wsf + (size_t)layer*16384; break;
    case 3: src = Wsb + (size_t)layer*16384; break;
    case 4: src = Wcp + (size_t)layer*32768; break;
    case 5: src = Wcp + (size_t)layer*32768; kOff = 128; break;
    case 6: src = Wcs + (size_t)layer*32768; break;
    default: src = Wcs + (size_t)layer*32768; kOff = 128; break;
  }
  wt[idx] = f2bf(src[(size_t)(kOff + k)*DF + n]);
}

// ---------------- segment-mean aggregation: coalesced index load + 4-deep gather ----------------
__global__ __launch_bounds__(256) void k_agg_all(
    const uint16_t* __restrict__ hp, const uint16_t* __restrict__ hs,
    const int* __restrict__ rpAll, int A1, int A2, int A3,
    const int* __restrict__ c0, const int* __restrict__ c1,
    const int* __restrict__ c2, const int* __restrict__ c3,
    uint16_t* __restrict__ o0, uint16_t* __restrict__ o1,
    uint16_t* __restrict__ o2, uint16_t* __restrict__ o3,
    int Np, int Ns, int gp, int gs){
  int b = blockIdx.x, w = threadIdx.x >> 6, lane = threadIdx.x & 63;
  const uint16_t* x; const int* rp; const int* col; uint16_t* out; int n, row;
  if (b < gp)            { x=hp; rp=rpAll;    col=c0; out=o0; n=Np; row=b*4+w; }
  else if (b < 2*gp)     { x=hp; rp=rpAll+A1; col=c1; out=o1; n=Np; row=(b-gp)*4+w; }
  else if (b < 2*gp+gs)  { x=hs; rp=rpAll+A2; col=c2; out=o2; n=Ns; row=(b-2*gp)*4+w; }
  else                   { x=hs; rp=rpAll+A3; col=c3; out=o3; n=Ns; row=(b-2*gp-gs)*4+w; }
  if (row >= n) return;
  int beg = rp[row], end = rp[row+1];
  int deg = end - beg;
  // one coalesced load of up to 64 indices; broadcast via shfl
  int cidx = beg + lane;
  int cl = (cidx < end) ? col[cidx] : 0;
  int dd = (deg > 64) ? 64 : deg;
  float a0=0.f,a1=0.f,b0=0.f,b1=0.f,cc0=0.f,cc1=0.f,d0=0.f,d1=0.f;
  int e = 0;
  for (; e+3 < dd; e += 4){            // 4 independent gathers in flight
    int s0 = __shfl(cl, e),   s1 = __shfl(cl, e+1);
    int s2 = __shfl(cl, e+2), s3 = __shfl(cl, e+3);
    uint32_t u0 = *(const uint32_t*)(x + ((size_t)s0<<7) + (lane<<1));
    uint32_t u1 = *(const uint32_t*)(x + ((size_t)s1<<7) + (lane<<1));
    uint32_t u2 = *(const uint32_t*)(x + ((size_t)s2<<7) + (lane<<1));
    uint32_t u3 = *(const uint32_t*)(x + ((size_t)s3<<7) + (lane<<1));
    a0  += bf2f(u0 & 0xffffu); a1  += bf2f(u0 >> 16);
    b0  += bf2f(u1 & 0xffffu); b1  += bf2f(u1 >> 16);
    cc0 += bf2f(u2 & 0xffffu); cc1 += bf2f(u2 >> 16);
    d0  += bf2f(u3 & 0xffffu); d1  += bf2f(u3 >> 16);
  }
  for (; e < dd; ++e){
    int s0 = __shfl(cl, e);
    uint32_t u0 = *(const uint32_t*)(x + ((size_t)s0<<7) + (lane<<1));
    a0 += bf2f(u0 & 0xffffu); a1 += bf2f(u0 >> 16);
  }
  if (deg > 64){                        // rare fallback
    for (int e2 = beg+64; e2 < end; ++e2){
      int s = col[e2];
      uint32_t u = *(const uint32_t*)(x + ((size_t)s<<7) + (lane<<1));
      a0 += bf2f(u & 0xffffu); a1 += bf2f(u >> 16);
    }
  }
  float s0f = (a0+b0)+(cc0+d0), s1f = (a1+b1)+(cc1+d1);
  float inv = 1.0f / fmaxf((float)deg, 1.0f);
  uint32_t pk = (uint32_t)f2bf(s0f*inv) | ((uint32_t)f2bf(s1f*inv) << 16);
  *(uint32_t*)(out + ((size_t)row<<7) + (lane<<1)) = pk;
}

// ---------------- fused per-layer GEMM: dir-f, dir-b, concat (2 passes) ----------------
__device__ __forceinline__ void stageA(uint16_t (*sA)[128], const uint16_t* __restrict__ Ap,
                                       int m0, int M, int t){
#pragma unroll
  for (int i=0;i<4;++i){
    int c = t + i*256, r = c>>4, ch = c&15;
    int gr = m0 + r;
    uint4 val = {0u,0u,0u,0u};
    if (gr < M) val = *(const uint4*)(Ap + (size_t)gr*DF + (ch<<3));
    *(uint4*)(&sA[r][(ch ^ (r&7))<<3]) = val;
  }
}
__device__ __forceinline__ void stageW(uint16_t (*sW)[128], const uint16_t* __restrict__ Wp, int t){
#pragma unroll
  for (int i=0;i<8;++i){
    int c = t + i*256, r = c>>4, ch = c&15;
    *(uint4*)(&sW[r][(ch ^ (r&7))<<3]) = *(const uint4*)(Wp + (size_t)r*DF + (ch<<3));
  }
}
__device__ __forceinline__ void mfma_pass(const uint16_t (*sA)[128], const uint16_t (*sW)[128],
                                          f32x4* acc, int w, int lane){
  int ar = (w<<4) + (lane&15);
  int q  = lane>>4;
#pragma unroll
  for (int kc=0;kc<4;++kc){
    int ch = kc*4 + q;
    bf16x8 afrag = *(const bf16x8*)(&sA[ar][(ch ^ (ar&7))<<3]);
#pragma unroll
    for (int n=0;n<8;++n){
      int br = (n<<4)+(lane&15);
      bf16x8 bfrag = *(const bf16x8*)(&sW[br][(ch ^ (br&7))<<3]);
      acc[n] = __builtin_amdgcn_mfma_f32_16x16x32_bf16(afrag, bfrag, acc[n], 0, 0, 0);
    }
  }
}
// bias + LeakyReLU + bf16, written back to the wave-private rows of the LDS tile
__device__ __forceinline__ void store_act_lds(uint16_t (*sA)[128], const f32x4* acc,
                                              const float* __restrict__ bias, int w, int lane){
#pragma unroll
  for (int n=0;n<8;++n){
    int cv = (n<<4) + (lane&15);
    float bv = bias[cv];
#pragma unroll
    for (int r=0;r<4;++r){
      int lr = (w<<4) + ((lane>>4)<<2) + r;
      float v = acc[n][r] + bv;
      v = (v > 0.f) ? v : 0.01f*v;
      sA[lr][(((cv>>3) ^ (lr&7))<<3) + (cv&7)] = f2bf(v);
    }
  }
}

template<int OUTF32>
__global__ __launch_bounds__(256) void k_layer(
    const uint16_t* __restrict__ Afp, const uint16_t* __restrict__ Abp,
    const uint16_t* __restrict__ Afs, const uint16_t* __restrict__ Abs,
    const uint16_t* __restrict__ wtl,
    const float* __restrict__ bpf, const float* __restrict__ bpb, const float* __restrict__ bcp,
    const float* __restrict__ bsf, const float* __restrict__ bsb, const float* __restrict__ bcs,
    uint16_t* __restrict__ hpb, uint16_t* __restrict__ hsb,
    float* __restrict__ outP, float* __restrict__ outS,
    int Np, int Ns, int bp){
  __shared__ uint16_t sF[64][128];
  __shared__ uint16_t sB[64][128];
  __shared__ uint16_t sW[128][128];
  int b = blockIdx.x, t = threadIdx.x, w = t>>6, lane = t&63;
  const uint16_t *Af,*Ab,*wf,*wb,*wct,*wcb; const float *bf_,*bb_,*bc_;
  uint16_t* hb; float* of; int M, lb;
  if (b < bp){
    Af=Afp; Ab=Abp; wf=wtl; wb=wtl+16384; wct=wtl+4*16384; wcb=wtl+5*16384;
    bf_=bpf; bb_=bpb; bc_=bcp; hb=hpb; of=outP; M=Np; lb=b;
  } else {
    Af=Afs; Ab=Abs; wf=wtl+2*16384; wb=wtl+3*16384; wct=wtl+6*16384; wcb=wtl+7*16384;
    bf_=bsf; bb_=bsb; bc_=bcs; hb=hsb; of=outS; M=Ns; lb=b-bp;
  }
  int m0 = lb*64;

  f32x4 accF[8], accB[8], accC[8];
#pragma unroll
  for (int n=0;n<8;++n){ accF[n]=(f32x4){0,0,0,0}; accB[n]=(f32x4){0,0,0,0}; accC[n]=(f32x4){0,0,0,0}; }

  stageA(sF, Af, m0, M, t);
  stageA(sB, Ab, m0, M, t);
  stageW(sW, wf, t);
  __syncthreads();
  mfma_pass(sF, sW, accF, w, lane);     // fp_raw = Af @ Wf
  __syncthreads();
  stageW(sW, wb, t);
  __syncthreads();
  mfma_pass(sB, sW, accB, w, lane);     // bp_raw = Ab @ Wb
  store_act_lds(sF, accF, bf_, w, lane);  // fp = act(fp_raw + bf) -> sF (wave-private rows)
  store_act_lds(sB, accB, bb_, w, lane);  // bp -> sB
  __syncthreads();
  stageW(sW, wct, t);
  __syncthreads();
  mfma_pass(sF, sW, accC, w, lane);     // h += fp @ Wc_top
  __syncthreads();
  stageW(sW, wcb, t);
  __syncthreads();
  mfma_pass(sB, sW, accC, w, lane);     // h += bp @ Wc_bot

#pragma unroll
  for (int n=0;n<8;++n){
    int cv = (n<<4)+(lane&15);
    float bv = bc_[cv];
#pragma unroll
    for (int r=0;r<4;++r){
      int lr = (w<<4)+((lane>>4)<<2)+r;
      int grow = m0 + lr;
      if (grow < M){
        float v = accC[n][r] + bv;
        if (OUTF32) of[(size_t)grow*DF + cv] = v;
        else        hb[(size_t)grow*DF + cv] = f2bf(v);
      }
    }
  }
}

// ---------------- host ----------------
extern "C" void kernel_launch(void* const* d_in, const int* in_sizes, int n_in,
                              void* d_out, int out_size, void* d_ws, size_t ws_size,
                              hipStream_t stream){
  const float* x_paper = (const float*)d_in[0];
  const float* x_snap  = (const float*)d_in[1];
  const int* src_pf = (const int*)d_in[2]; const int* dst_pf = (const int*)d_in[3];
  const int* src_pb = (const int*)d_in[4]; const int* dst_pb = (const int*)d_in[5];
  const int* src_sf = (const int*)d_in[6]; const int* dst_sf = (const int*)d_in[7];
  const int* src_sb = (const int*)d_in[8]; const int* dst_sb = (const int*)d_in[9];
  const float* Wpf = (const float*)d_in[10]; const float* bpf = (const float*)d_in[11];
  const float* Wsf = (const float*)d_in[12]; const float* bsf = (const float*)d_in[13];
  const float* Wpb = (const float*)d_in[14]; const float* bpb = (const float*)d_in[15];
  const float* Wsb = (const float*)d_in[16]; const float* bsb = (const float*)d_in[17];
  const float* Wcp = (const float*)d_in[18]; const float* bcp = (const float*)d_in[19];
  const float* Wcs = (const float*)d_in[20]; const float* bcs = (const float*)d_in[21];

  const int Np = in_sizes[0]/DF, Ns = in_sizes[1]/DF;
  const int Ep = in_sizes[2],    Es = in_sizes[6];
  const int K  = in_sizes[10]/(DF*DF);

  const int P1 = ((Np + 1 + 1023)/1024)*1024;
  const int Ps = ((Ns + 1 + 1023)/1024)*1024;
  const int A1 = P1, A2 = 2*P1, A3 = 2*P1 + Ps, NT = 2*P1 + 2*Ps;
  const int B1 = Ep, B2 = 2*Ep, B3 = 2*Ep + Es;

  uint8_t* base = (uint8_t*)d_ws;
  size_t off = 0;
  auto carve = [&](size_t bytes)->void*{
    void* p = base + off;
    off = (off + bytes + 255) & ~(size_t)255;
    return p;
  };

  int* degAll = (int*)carve((size_t)NT*4);
  int* rpAll  = (int*)carve((size_t)NT*4);
  int* curAll = (int*)carve((size_t)NT*4);
  int* bsum   = (int*)carve(4096*4);
  int* col0 = (int*)carve((size_t)Ep*4);
  int* col1 = (int*)carve((size_t)Ep*4);
  int* col2 = (int*)carve((size_t)Es*4);
  int* col3 = (int*)carve((size_t)Es*4);
  uint16_t* wt   = (uint16_t*)carve((size_t)K*8*16384*2);
  uint16_t* hp_b = (uint16_t*)carve((size_t)Np*DF*2);
  uint16_t* hs_b = (uint16_t*)carve((size_t)Ns*DF*2);
  uint16_t* Afp  = (uint16_t*)carve((size_t)Np*DF*2);
  uint16_t* Abp  = (uint16_t*)carve((size_t)Np*DF*2);
  uint16_t* Afs  = (uint16_t*)carve((size_t)Ns*DF*2);
  uint16_t* Abs  = (uint16_t*)carve((size_t)Ns*DF*2);

  const int Etot = 2*Ep + 2*Es;
  int eblk = (Etot + 255)/256; if (eblk > 2048) eblk = 2048;

  // CSR build
  k_zero<<<(NT+255)/256, 256, 0, stream>>>(degAll, NT);
  k_count_all<<<eblk, 256, 0, stream>>>(dst_pf, dst_pb, dst_sf, dst_sb, degAll, Ep, Es, A1, A2, A3);
  k_scan1<<<NT/1024, 256, 0, stream>>>(degAll, rpAll, bsum, NT);
  k_scan2<<<1, 256, 0, stream>>>(bsum, NT/1024);
  k_add_all<<<(NT+255)/256, 256, 0, stream>>>(rpAll, curAll, bsum, A1, A2, A3, B1, B2, B3, NT);
  k_fill_all<<<eblk, 256, 0, stream>>>(src_pf, dst_pf, src_pb, dst_pb, src_sf, dst_sf, src_sb, dst_sb,
                                       curAll, col0, col1, col2, col3, Ep, Es, A1, A2, A3);

  const int npE = Np*DF, total4 = (Np + Ns)*DF/4;
  k_cast<<<(total4+255)/256, 256, 0, stream>>>(x_paper, x_snap, hp_b, hs_b, npE, total4);
  k_transpose_all<<<(K*8*16384+255)/256, 256, 0, stream>>>(Wpf, Wpb, Wsf, Wsb, Wcp, Wcs, wt, K);

  float* outP = (float*)d_out;
  float* outS = outP + (size_t)Np*DF;
  const int gp = (Np+3)/4, gs = (Ns+3)/4;
  const int bp = (Np+63)/64, bs = (Ns+63)/64;

  for (int i=0; i<K; ++i){
    const uint16_t* wtl = wt + (size_t)i*8*16384;
    k_agg_all<<<2*gp + 2*gs, 256, 0, stream>>>(hp_b, hs_b, rpAll, A1, A2, A3,
                                               col0, col1, col2, col3,
                                               Afp, Abp, Afs, Abs, Np, Ns, gp, gs);
    if (i == K-1)
      k_layer<1><<<bp + bs, 256, 0, stream>>>(Afp, Abp, Afs, Abs, wtl,
                                              bpf + (size_t)i*DF, bpb + (size_t)i*DF, bcp + (size_t)i*DF,
                                              bsf + (size_t)i*DF, bsb + (size_t)i*DF, bcs + (size_t)i*DF,
                                              hp_b, hs_b, outP, outS, Np, Ns, bp);
    else
      k_layer<0><<<bp + bs, 256, 0, stream>>>(Afp, Abp, Afs, Abs, wtl,
                                              bpf + (size_t)i*DF, bpb + (size_t)i*DF, bcp + (size_t)i*DF,
                                              bsf + (size_t)i*DF, bsb + (size_t)i*DF, bcs + (size_t)i*DF,
                                              hp_b, hs_b, outP, outS, Np, Ns, bp);
  }
}

// Round 8
// 1265.370 us; speedup vs baseline: 1.4158x; 1.0870x over previous
//
#include <hip/hip_runtime.h>
#include <stdint.h>

#define DF 128

typedef __attribute__((ext_vector_type(8))) short bf16x8;
typedef __attribute__((ext_vector_type(4))) float f32x4;

__device__ __forceinline__ float bf2f(uint32_t b){ union{uint32_t u; float f;} c; c.u = b<<16; return c.f; }
__device__ __forceinline__ uint16_t f2bf(float f){
  union{float f; uint32_t u;} c; c.f = f;
  return (uint16_t)((c.u + 0x7fffu + ((c.u>>16)&1u))>>16);
}

// ---------------- CSR build (all 4 edge sets in one padded layout) ----------------
__global__ __launch_bounds__(256) void k_zero(int* __restrict__ p, int n){
  int i = blockIdx.x*256 + threadIdx.x;
  if (i < n) p[i] = 0;
}

// XCD-windowed count: group g (blockIdx&7 -> XCD g) only touches dst in its window,
// so each deg line is dirtied by exactly one XCD L2 (no cross-XCD line ping-pong).
__global__ __launch_bounds__(256) void k_count_allw(
    const int* __restrict__ d0, const int* __restrict__ d1,
    const int* __restrict__ d2, const int* __restrict__ d3,
    int* __restrict__ deg, int Ep, int Es, int A1, int A2, int A3,
    int wp, int wsn){
  int g  = blockIdx.x & 7;
  int T  = (gridDim.x >> 3) * 256;
  int tid = (blockIdx.x >> 3)*256 + threadIdx.x;
  int plo = g*wp,  phi = plo + wp;
  int slo = g*wsn, shi = slo + wsn;
  int Etot = 2*Ep + 2*Es;
  for (int e = tid; e < Etot; e += T){
    if (e < Ep){           int d = d0[e];          if (d>=plo && d<phi) atomicAdd(&deg[d], 1); }
    else if (e < 2*Ep){    int d = d1[e-Ep];       if (d>=plo && d<phi) atomicAdd(&deg[A1+d], 1); }
    else if (e < 2*Ep+Es){ int d = d2[e-2*Ep];     if (d>=slo && d<shi) atomicAdd(&deg[A2+d], 1); }
    else{                  int d = d3[e-2*Ep-Es];  if (d>=slo && d<shi) atomicAdd(&deg[A3+d], 1); }
  }
}

__global__ __launch_bounds__(256) void k_scan1(const int* __restrict__ in, int* __restrict__ out,
                                               int* __restrict__ bsum, int n){
  __shared__ int lds[256];
  int t = threadIdx.x;
  int base = blockIdx.x*1024 + t*4;
  int v0 = (base+0<n)?in[base+0]:0, v1 = (base+1<n)?in[base+1]:0;
  int v2 = (base+2<n)?in[base+2]:0, v3 = (base+3<n)?in[base+3]:0;
  int ts = v0+v1+v2+v3;
  lds[t] = ts; __syncthreads();
  for (int off=1; off<256; off<<=1){
    int x = (t>=off)?lds[t-off]:0; __syncthreads();
    lds[t] += x; __syncthreads();
  }
  int incl = lds[t];
  if (t==255) bsum[blockIdx.x] = incl;
  int run = incl - ts;
  if (base+0<n) out[base+0]=run; run+=v0;
  if (base+1<n) out[base+1]=run; run+=v1;
  if (base+2<n) out[base+2]=run; run+=v2;
  if (base+3<n) out[base+3]=run;
}

__global__ __launch_bounds__(256) void k_scan2(int* __restrict__ s, int nb){
  __shared__ int lds[256];
  __shared__ int carry;
  int t = threadIdx.x;
  if (t==0) carry = 0;
  __syncthreads();
  for (int b0=0; b0<nb; b0+=1024){
    int base = b0 + t*4;
    int v0 = (base+0<nb)?s[base+0]:0, v1 = (base+1<nb)?s[base+1]:0;
    int v2 = (base+2<nb)?s[base+2]:0, v3 = (base+3<nb)?s[base+3]:0;
    int ts = v0+v1+v2+v3;
    lds[t] = ts; __syncthreads();
    for (int off=1; off<256; off<<=1){
      int x = (t>=off)?lds[t-off]:0; __syncthreads();
      lds[t] += x; __syncthreads();
    }
    int incl = lds[t];
    int tot  = lds[255];
    int c0   = carry;
    __syncthreads();
    int run = incl - ts + c0;
    if (base+0<nb) s[base+0]=run; run+=v0;
    if (base+1<nb) s[base+1]=run; run+=v1;
    if (base+2<nb) s[base+2]=run; run+=v2;
    if (base+3<nb) s[base+3]=run;
    if (t==0) carry = c0 + tot;
    __syncthreads();
  }
}

__global__ __launch_bounds__(256) void k_add_all(int* __restrict__ rp, int* __restrict__ cur,
                                                 const int* __restrict__ bsum,
                                                 int A1, int A2, int A3,
                                                 int B1, int B2, int B3, int NT){
  int i = blockIdx.x*256 + threadIdx.x;
  if (i >= NT) return;
  int b = (i < A1) ? 0 : (i < A2) ? B1 : (i < A3) ? B2 : B3;
  int v = rp[i] + bsum[i>>10] - b;
  rp[i] = v; cur[i] = v;
}

// XCD-windowed fill: col/cur lines for window g live only in XCD g's L2 ->
// scattered 4B writes coalesce before writeback (212 MB -> ~payload).
__global__ __launch_bounds__(256) void k_fill_allw(
    const int* __restrict__ s0, const int* __restrict__ d0,
    const int* __restrict__ s1, const int* __restrict__ d1,
    const int* __restrict__ s2, const int* __restrict__ d2,
    const int* __restrict__ s3, const int* __restrict__ d3,
    int* __restrict__ cur,
    int* __restrict__ c0, int* __restrict__ c1, int* __restrict__ c2, int* __restrict__ c3,
    int Ep, int Es, int A1, int A2, int A3, int wp, int wsn){
  int g  = blockIdx.x & 7;
  int T  = (gridDim.x >> 3) * 256;
  int tid = (blockIdx.x >> 3)*256 + threadIdx.x;
  int plo = g*wp,  phi = plo + wp;
  int slo = g*wsn, shi = slo + wsn;
  int Etot = 2*Ep + 2*Es;
  for (int e = tid; e < Etot; e += T){
    if (e < Ep){
      int d = d0[e];
      if (d>=plo && d<phi){ int p = atomicAdd(&cur[d], 1); c0[p] = s0[e]; }
    } else if (e < 2*Ep){
      int q = e-Ep; int d = d1[q];
      if (d>=plo && d<phi){ int p = atomicAdd(&cur[A1+d], 1); c1[p] = s1[q]; }
    } else if (e < 2*Ep+Es){
      int q = e-2*Ep; int d = d2[q];
      if (d>=slo && d<shi){ int p = atomicAdd(&cur[A2+d], 1); c2[p] = s2[q]; }
    } else {
      int q = e-2*Ep-Es; int d = d3[q];
      if (d>=slo && d<shi){ int p = atomicAdd(&cur[A3+d], 1); c3[p] = s3[q]; }
    }
  }
}

// ---------------- f32 -> bf16 feature cast ----------------
__global__ __launch_bounds__(256) void k_cast(const float* __restrict__ xp, const float* __restrict__ xs,
                                              uint16_t* __restrict__ hp, uint16_t* __restrict__ hs,
                                              int npE, int total4){
  int i = blockIdx.x*256 + threadIdx.x;
  if (i >= total4) return;
  int e = i*4;
  const float* src; uint16_t* dst; int o;
  if (e < npE){ src = xp; dst = hp; o = e; }
  else        { src = xs; dst = hs; o = e - npE; }
  float4 v = *(const float4*)(src + o);
  ushort4 u;
  u.x = f2bf(v.x); u.y = f2bf(v.y); u.z = f2bf(v.z); u.w = f2bf(v.w);
  *(ushort4*)(dst + o) = u;
}

// ---------------- weight transpose+cast ----------------
__global__ __launch_bounds__(256) void k_transpose_all(
    const float* __restrict__ Wpf, const float* __restrict__ Wpb,
    const float* __restrict__ Wsf, const float* __restrict__ Wsb,
    const float* __restrict__ Wcp, const float* __restrict__ Wcs,
    uint16_t* __restrict__ wt, int K){
  int idx = blockIdx.x*256 + threadIdx.x;
  if (idx >= K*8*16384) return;
  int ls = idx >> 14, layer = ls >> 3, slot = ls & 7;
  int within = idx & 16383, n = within >> 7, k = within & 127;
  const float* src; int kOff = 0;
  switch (slot){
    case 0: src = Wpf + (size_t)layer*16384; break;
    case 1: src = Wpb + (size_t)layer*16384; break;
    case 2: src = Wsf + (size_t)layer*16384; break;
    case 3: src = Wsb + (size_t)layer*16384; break;
    case 4: src = Wcp + (size_t)layer*32768; break;
    case 5: src = Wcp + (size_t)layer*32768; kOff = 128; break;
    case 6: src = Wcs + (size_t)layer*32768; break;
    default: src = Wcs + (size_t)layer*32768; kOff = 128; break;
  }
  wt[idx] = f2bf(src[(size_t)(kOff + k)*DF + n]);
}

// ---------------- segment-mean aggregation: coalesced index load + 4-deep gather ----------------
__global__ __launch_bounds__(256) void k_agg_all(
    const uint16_t* __restrict__ hp, const uint16_t* __restrict__ hs,
    const int* __restrict__ rpAll, int A1, int A2, int A3,
    const int* __restrict__ c0, const int* __restrict__ c1,
    const int* __restrict__ c2, const int* __restrict__ c3,
    uint16_t* __restrict__ o0, uint16_t* __restrict__ o1,
    uint16_t* __restrict__ o2, uint16_t* __restrict__ o3,
    int Np, int Ns, int gp, int gs){
  int b = blockIdx.x, w = threadIdx.x >> 6, lane = threadIdx.x & 63;
  const uint16_t* x; const int* rp; const int* col; uint16_t* out; int n, row;
  if (b < gp)            { x=hp; rp=rpAll;    col=c0; out=o0; n=Np; row=b*4+w; }
  else if (b < 2*gp)     { x=hp; rp=rpAll+A1; col=c1; out=o1; n=Np; row=(b-gp)*4+w; }
  else if (b < 2*gp+gs)  { x=hs; rp=rpAll+A2; col=c2; out=o2; n=Ns; row=(b-2*gp)*4+w; }
  else                   { x=hs; rp=rpAll+A3; col=c3; out=o3; n=Ns; row=(b-2*gp-gs)*4+w; }
  if (row >= n) return;
  int beg = rp[row], end = rp[row+1];
  int deg = end - beg;
  int cidx = beg + lane;
  int cl = (cidx < end) ? col[cidx] : 0;
  int dd = (deg > 64) ? 64 : deg;
  float a0=0.f,a1=0.f,b0=0.f,b1=0.f,cc0=0.f,cc1=0.f,d0=0.f,d1=0.f;
  int e = 0;
  for (; e+3 < dd; e += 4){
    int s0 = __shfl(cl, e),   s1 = __shfl(cl, e+1);
    int s2 = __shfl(cl, e+2), s3 = __shfl(cl, e+3);
    uint32_t u0 = *(const uint32_t*)(x + ((size_t)s0<<7) + (lane<<1));
    uint32_t u1 = *(const uint32_t*)(x + ((size_t)s1<<7) + (lane<<1));
    uint32_t u2 = *(const uint32_t*)(x + ((size_t)s2<<7) + (lane<<1));
    uint32_t u3 = *(const uint32_t*)(x + ((size_t)s3<<7) + (lane<<1));
    a0  += bf2f(u0 & 0xffffu); a1  += bf2f(u0 >> 16);
    b0  += bf2f(u1 & 0xffffu); b1  += bf2f(u1 >> 16);
    cc0 += bf2f(u2 & 0xffffu); cc1 += bf2f(u2 >> 16);
    d0  += bf2f(u3 & 0xffffu); d1  += bf2f(u3 >> 16);
  }
  for (; e < dd; ++e){
    int s0 = __shfl(cl, e);
    uint32_t u0 = *(const uint32_t*)(x + ((size_t)s0<<7) + (lane<<1));
    a0 += bf2f(u0 & 0xffffu); a1 += bf2f(u0 >> 16);
  }
  if (deg > 64){
    for (int e2 = beg+64; e2 < end; ++e2){
      int s = col[e2];
      uint32_t u = *(const uint32_t*)(x + ((size_t)s<<7) + (lane<<1));
      a0 += bf2f(u & 0xffffu); a1 += bf2f(u >> 16);
    }
  }
  float s0f = (a0+b0)+(cc0+d0), s1f = (a1+b1)+(cc1+d1);
  float inv = 1.0f / fmaxf((float)deg, 1.0f);
  uint32_t pk = (uint32_t)f2bf(s0f*inv) | ((uint32_t)f2bf(s1f*inv) << 16);
  *(uint32_t*)(out + ((size_t)row<<7) + (lane<<1)) = pk;
}

// ---------------- fused per-layer GEMM: dir-f, dir-b, concat (2 passes) ----------------
__device__ __forceinline__ void stageA(uint16_t (*sA)[128], const uint16_t* __restrict__ Ap,
                                       int m0, int M, int t){
#pragma unroll
  for (int i=0;i<4;++i){
    int c = t + i*256, r = c>>4, ch = c&15;
    int gr = m0 + r;
    uint4 val = {0u,0u,0u,0u};
    if (gr < M) val = *(const uint4*)(Ap + (size_t)gr*DF + (ch<<3));
    *(uint4*)(&sA[r][(ch ^ (r&7))<<3]) = val;
  }
}
__device__ __forceinline__ void stageW(uint16_t (*sW)[128], const uint16_t* __restrict__ Wp, int t){
#pragma unroll
  for (int i=0;i<8;++i){
    int c = t + i*256, r = c>>4, ch = c&15;
    *(uint4*)(&sW[r][(ch ^ (r&7))<<3]) = *(const uint4*)(Wp + (size_t)r*DF + (ch<<3));
  }
}
__device__ __forceinline__ void mfma_pass(const uint16_t (*sA)[128], const uint16_t (*sW)[128],
                                          f32x4* acc, int w, int lane){
  int ar = (w<<4) + (lane&15);
  int q  = lane>>4;
#pragma unroll
  for (int kc=0;kc<4;++kc){
    int ch = kc*4 + q;
    bf16x8 afrag = *(const bf16x8*)(&sA[ar][(ch ^ (ar&7))<<3]);
#pragma unroll
    for (int n=0;n<8;++n){
      int br = (n<<4)+(lane&15);
      bf16x8 bfrag = *(const bf16x8*)(&sW[br][(ch ^ (br&7))<<3]);
      acc[n] = __builtin_amdgcn_mfma_f32_16x16x32_bf16(afrag, bfrag, acc[n], 0, 0, 0);
    }
  }
}
__device__ __forceinline__ void store_act_lds(uint16_t (*sA)[128], const f32x4* acc,
                                              const float* __restrict__ bias, int w, int lane){
#pragma unroll
  for (int n=0;n<8;++n){
    int cv = (n<<4) + (lane&15);
    float bv = bias[cv];
#pragma unroll
    for (int r=0;r<4;++r){
      int lr = (w<<4) + ((lane>>4)<<2) + r;
      float v = acc[n][r] + bv;
      v = (v > 0.f) ? v : 0.01f*v;
      sA[lr][(((cv>>3) ^ (lr&7))<<3) + (cv&7)] = f2bf(v);
    }
  }
}

template<int OUTF32>
__global__ __launch_bounds__(256) void k_layer(
    const uint16_t* __restrict__ Afp, const uint16_t* __restrict__ Abp,
    const uint16_t* __restrict__ Afs, const uint16_t* __restrict__ Abs,
    const uint16_t* __restrict__ wtl,
    const float* __restrict__ bpf, const float* __restrict__ bpb, const float* __restrict__ bcp,
    const float* __restrict__ bsf, const float* __restrict__ bsb, const float* __restrict__ bcs,
    uint16_t* __restrict__ hpb, uint16_t* __restrict__ hsb,
    float* __restrict__ outP, float* __restrict__ outS,
    int Np, int Ns, int bp){
  __shared__ uint16_t sF[64][128];
  __shared__ uint16_t sB[64][128];
  __shared__ uint16_t sW[128][128];
  int b = blockIdx.x, t = threadIdx.x, w = t>>6, lane = t&63;
  const uint16_t *Af,*Ab,*wf,*wb,*wct,*wcb; const float *bf_,*bb_,*bc_;
  uint16_t* hb; float* of; int M, lb;
  if (b < bp){
    Af=Afp; Ab=Abp; wf=wtl; wb=wtl+16384; wct=wtl+4*16384; wcb=wtl+5*16384;
    bf_=bpf; bb_=bpb; bc_=bcp; hb=hpb; of=outP; M=Np; lb=b;
  } else {
    Af=Afs; Ab=Abs; wf=wtl+2*16384; wb=wtl+3*16384; wct=wtl+6*16384; wcb=wtl+7*16384;
    bf_=bsf; bb_=bsb; bc_=bcs; hb=hsb; of=outS; M=Ns; lb=b-bp;
  }
  int m0 = lb*64;

  f32x4 accF[8], accB[8], accC[8];
#pragma unroll
  for (int n=0;n<8;++n){ accF[n]=(f32x4){0,0,0,0}; accB[n]=(f32x4){0,0,0,0}; accC[n]=(f32x4){0,0,0,0}; }

  stageA(sF, Af, m0, M, t);
  stageA(sB, Ab, m0, M, t);
  stageW(sW, wf, t);
  __syncthreads();
  mfma_pass(sF, sW, accF, w, lane);     // fp_raw = Af @ Wf
  __syncthreads();
  stageW(sW, wb, t);
  __syncthreads();
  mfma_pass(sB, sW, accB, w, lane);     // bp_raw = Ab @ Wb
  store_act_lds(sF, accF, bf_, w, lane);  // fp -> sF (wave-private rows)
  store_act_lds(sB, accB, bb_, w, lane);  // bp -> sB
  __syncthreads();
  stageW(sW, wct, t);
  __syncthreads();
  mfma_pass(sF, sW, accC, w, lane);     // h += fp @ Wc_top
  __syncthreads();
  stageW(sW, wcb, t);
  __syncthreads();
  mfma_pass(sB, sW, accC, w, lane);     // h += bp @ Wc_bot

#pragma unroll
  for (int n=0;n<8;++n){
    int cv = (n<<4)+(lane&15);
    float bv = bc_[cv];
#pragma unroll
    for (int r=0;r<4;++r){
      int lr = (w<<4)+((lane>>4)<<2)+r;
      int grow = m0 + lr;
      if (grow < M){
        float v = accC[n][r] + bv;
        if (OUTF32) of[(size_t)grow*DF + cv] = v;
        else        hb[(size_t)grow*DF + cv] = f2bf(v);
      }
    }
  }
}

// ---------------- host ----------------
extern "C" void kernel_launch(void* const* d_in, const int* in_sizes, int n_in,
                              void* d_out, int out_size, void* d_ws, size_t ws_size,
                              hipStream_t stream){
  const float* x_paper = (const float*)d_in[0];
  const float* x_snap  = (const float*)d_in[1];
  const int* src_pf = (const int*)d_in[2]; const int* dst_pf = (const int*)d_in[3];
  const int* src_pb = (const int*)d_in[4]; const int* dst_pb = (const int*)d_in[5];
  const int* src_sf = (const int*)d_in[6]; const int* dst_sf = (const int*)d_in[7];
  const int* src_sb = (const int*)d_in[8]; const int* dst_sb = (const int*)d_in[9];
  const float* Wpf = (const float*)d_in[10]; const float* bpf = (const float*)d_in[11];
  const float* Wsf = (const float*)d_in[12]; const float* bsf = (const float*)d_in[13];
  const float* Wpb = (const float*)d_in[14]; const float* bpb = (const float*)d_in[15];
  const float* Wsb = (const float*)d_in[16]; const float* bsb = (const float*)d_in[17];
  const float* Wcp = (const float*)d_in[18]; const float* bcp = (const float*)d_in[19];
  const float* Wcs = (const float*)d_in[20]; const float* bcs = (const float*)d_in[21];

  const int Np = in_sizes[0]/DF, Ns = in_sizes[1]/DF;
  const int Ep = in_sizes[2],    Es = in_sizes[6];
  const int K  = in_sizes[10]/(DF*DF);

  const int P1 = ((Np + 1 + 1023)/1024)*1024;
  const int Ps = ((Ns + 1 + 1023)/1024)*1024;
  const int A1 = P1, A2 = 2*P1, A3 = 2*P1 + Ps, NT = 2*P1 + 2*Ps;
  const int B1 = Ep, B2 = 2*Ep, B3 = 2*Ep + Es;
  const int wp  = (Np + 7)/8;   // per-XCD dst window (papers)
  const int wsn = (Ns + 7)/8;   // per-XCD dst window (snaps)

  uint8_t* base = (uint8_t*)d_ws;
  size_t off = 0;
  auto carve = [&](size_t bytes)->void*{
    void* p = base + off;
    off = (off + bytes + 255) & ~(size_t)255;
    return p;
  };

  int* degAll = (int*)carve((size_t)NT*4);
  int* rpAll  = (int*)carve((size_t)NT*4);
  int* curAll = (int*)carve((size_t)NT*4);
  int* bsum   = (int*)carve(4096*4);
  int* col0 = (int*)carve((size_t)Ep*4);
  int* col1 = (int*)carve((size_t)Ep*4);
  int* col2 = (int*)carve((size_t)Es*4);
  int* col3 = (int*)carve((size_t)Es*4);
  uint16_t* wt   = (uint16_t*)carve((size_t)K*8*16384*2);
  uint16_t* hp_b = (uint16_t*)carve((size_t)Np*DF*2);
  uint16_t* hs_b = (uint16_t*)carve((size_t)Ns*DF*2);
  uint16_t* Afp  = (uint16_t*)carve((size_t)Np*DF*2);
  uint16_t* Abp  = (uint16_t*)carve((size_t)Np*DF*2);
  uint16_t* Afs  = (uint16_t*)carve((size_t)Ns*DF*2);
  uint16_t* Abs  = (uint16_t*)carve((size_t)Ns*DF*2);

  // CSR build (XCD-windowed count/fill; 2048 blocks = 256 per XCD group)
  k_zero<<<(NT+255)/256, 256, 0, stream>>>(degAll, NT);
  k_count_allw<<<2048, 256, 0, stream>>>(dst_pf, dst_pb, dst_sf, dst_sb, degAll,
                                         Ep, Es, A1, A2, A3, wp, wsn);
  k_scan1<<<NT/1024, 256, 0, stream>>>(degAll, rpAll, bsum, NT);
  k_scan2<<<1, 256, 0, stream>>>(bsum, NT/1024);
  k_add_all<<<(NT+255)/256, 256, 0, stream>>>(rpAll, curAll, bsum, A1, A2, A3, B1, B2, B3, NT);
  k_fill_allw<<<2048, 256, 0, stream>>>(src_pf, dst_pf, src_pb, dst_pb, src_sf, dst_sf, src_sb, dst_sb,
                                        curAll, col0, col1, col2, col3, Ep, Es, A1, A2, A3, wp, wsn);

  const int npE = Np*DF, total4 = (Np + Ns)*DF/4;
  k_cast<<<(total4+255)/256, 256, 0, stream>>>(x_paper, x_snap, hp_b, hs_b, npE, total4);
  k_transpose_all<<<(K*8*16384+255)/256, 256, 0, stream>>>(Wpf, Wpb, Wsf, Wsb, Wcp, Wcs, wt, K);

  float* outP = (float*)d_out;
  float* outS = outP + (size_t)Np*DF;
  const int gp = (Np+3)/4, gs = (Ns+3)/4;
  const int bp = (Np+63)/64, bs = (Ns+63)/64;

  for (int i=0; i<K; ++i){
    const uint16_t* wtl = wt + (size_t)i*8*16384;
    k_agg_all<<<2*gp + 2*gs, 256, 0, stream>>>(hp_b, hs_b, rpAll, A1, A2, A3,
                                               col0, col1, col2, col3,
                                               Afp, Abp, Afs, Abs, Np, Ns, gp, gs);
    if (i == K-1)
      k_layer<1><<<bp + bs, 256, 0, stream>>>(Afp, Abp, Afs, Abs, wtl,
                                              bpf + (size_t)i*DF, bpb + (size_t)i*DF, bcp + (size_t)i*DF,
                                              bsf + (size_t)i*DF, bsb + (size_t)i*DF, bcs + (size_t)i*DF,
                                              hp_b, hs_b, outP, outS, Np, Ns, bp);
    else
      k_layer<0><<<bp + bs, 256, 0, stream>>>(Afp, Abp, Afs, Abs, wtl,
                                              bpf + (size_t)i*DF, bpb + (size_t)i*DF, bcp + (size_t)i*DF,
                                              bsf + (size_t)i*DF, bsb + (size_t)i*DF, bcs + (size_t)i*DF,
                                              hp_b, hs_b, outP, outS, Np, Ns, bp);
  }
}